// Round 4
// baseline (792.469 us; speedup 1.0000x reference)
//
#include <hip/hip_runtime.h>
#include <hip/hip_bf16.h>

#define N_NODES 50000
#define N_EDGES 800000
#define DIM     128
#define N_STRIPS (N_NODES / 16)               // 3125 exact: 16-row strips
#define N_BKT    782                          // bucket = dst >> 6 (64 nodes/bucket)
#define CHUNK_E  4096                         // edges per scatter chunk
#define EDGE_CHUNKS 196                       // 195*4096 + 1280
#define BCAP     1536                         // bucket region cap (mean 1024, 16 sigma)
#define GEMM_BLOCKS 782                       // ceil(3125/4)
#define D1_BLOCKS (EDGE_CHUNKS + GEMM_BLOCKS + 8)  // 986
#define SUP_ROWS 50048                        // support rows incl. tail-strip slack
#define AGS      132                          // agg LDS row stride (f32): 16B-aligned, bank-spread

typedef short short8 __attribute__((ext_vector_type(8)));
typedef float floatx4 __attribute__((ext_vector_type(4)));

// fp32 -> bf16 (RNE) bit pattern
__device__ inline unsigned short f2bf(float f) {
    __hip_bfloat16 h = __float2bfloat16(f);
    return *reinterpret_cast<unsigned short*>(&h);
}

// ---------------------------------------------------------------------------
// Dispatch 1 (986 blocks):
//  [0,196):    bucket scatter via atomic range reservation (round-2 config)
//  [196,978):  GEMM1: inline W1->LDS fragment pack, MFMA, support writeout in
//              PERMUTED dword layout: support dword l of row r packs
//              (dim l, dim l+64) -> conflict-free LDS atomics in dispatch 2.
//  [978,986):  pack W2 (B[k][n]=W2[n][k]) -> pw2 (consumed by dispatch 2)
// Shared: 32 KB overlay (scatter: bh/rcur; GEMM1: W1 frags, then stg).
// ---------------------------------------------------------------------------
__global__ __launch_bounds__(256) void fused1(
    const float* __restrict__ x, const float* __restrict__ W1,
    const float* __restrict__ bias, const float* __restrict__ W2,
    const int* __restrict__ src, const int* __restrict__ dst,
    const float* __restrict__ vals,
    unsigned int* __restrict__ support, int* __restrict__ bcnt,
    int2* __restrict__ bucketed, uint4* __restrict__ p2)
{
    __shared__ __align__(16) char smem[32768];
    const int t = threadIdx.x;

    if (blockIdx.x < EDGE_CHUNKS) {
        // ---------------- bucket scatter ----------------
        int* bh   = (int*)smem;          // [800]
        int* rcur = (int*)smem + 800;    // [800]
        const int chunk = blockIdx.x;
        for (int i = t; i < 800; i += 256) bh[i] = 0;
        __syncthreads();
        const int base   = chunk * CHUNK_E;
        const int navail = min(CHUNK_E, N_EDGES - base); // 4096 or 1280; %4==0
        const int4* d4 = reinterpret_cast<const int4*>(dst + base);
        #pragma unroll
        for (int i = 0; i < 4; ++i) {
            const int j = t + i * 256;
            if (j * 4 < navail) {
                const int4 d = d4[j];
                atomicAdd(&bh[d.x >> 6], 1);
                atomicAdd(&bh[d.y >> 6], 1);
                atomicAdd(&bh[d.z >> 6], 1);
                atomicAdd(&bh[d.w >> 6], 1);
            }
        }
        __syncthreads();
        for (int b = t; b < N_BKT; b += 256)
            rcur[b] = b * BCAP + atomicAdd(&bcnt[b], bh[b]);
        __syncthreads();
        const int4*   s4 = reinterpret_cast<const int4*>(src + base);
        const float4* v4 = reinterpret_cast<const float4*>(vals + base);
        #pragma unroll
        for (int i = 0; i < 4; ++i) {
            const int j = t + i * 256;
            if (j * 4 < navail) {
                const int4   s = s4[j];
                const int4   d = d4[j];
                const float4 v = v4[j];
                int p;
                p = atomicAdd(&rcur[d.x >> 6], 1);
                bucketed[p] = make_int2((s.x & 0xFFFF) | ((d.x & 63) << 16), __float_as_int(v.x));
                p = atomicAdd(&rcur[d.y >> 6], 1);
                bucketed[p] = make_int2((s.y & 0xFFFF) | ((d.y & 63) << 16), __float_as_int(v.y));
                p = atomicAdd(&rcur[d.z >> 6], 1);
                bucketed[p] = make_int2((s.z & 0xFFFF) | ((d.z & 63) << 16), __float_as_int(v.z));
                p = atomicAdd(&rcur[d.w >> 6], 1);
                bucketed[p] = make_int2((s.w & 0xFFFF) | ((d.w & 63) << 16), __float_as_int(v.w));
            }
        }
    } else if (blockIdx.x < EDGE_CHUNKS + GEMM_BLOCKS) {
        // ---------------- GEMM1 ----------------
        const int gb    = blockIdx.x - EDGE_CHUNKS;      // 0..781
        const int wave  = t >> 6;
        const int lane  = t & 63;
        const int strip = gb * 4 + wave;
        const int m = lane & 15;
        const int q = lane >> 4;
        const bool valid = strip < N_STRIPS;             // block 781: waves 1-3 idle

        // cooperative W1 -> LDS fragment pack (coalesced global float4 reads)
        unsigned short* w1e = (unsigned short*)smem;     // element view: slot*8+j
        #pragma unroll
        for (int i = 0; i < 16; ++i) {
            const int f4 = t + i * 256;                  // 4096 float4 = 16384 elems
            const float4 v = reinterpret_cast<const float4*>(W1)[f4];
            const float vv[4] = {v.x, v.y, v.z, v.w};
            const int e0 = f4 * 4;
            #pragma unroll
            for (int j = 0; j < 4; ++j) {
                const int k = (e0 + j) >> 7, n = (e0 + j) & 127;
                const int ks = k >> 5, qq = (k >> 3) & 3, jj = k & 7;
                const int nt = n >> 4, mm = n & 15;
                w1e[((ks * 8 + nt) * 64 + qq * 16 + mm) * 8 + jj] = f2bf(vv[j]);
            }
        }
        __syncthreads();

        floatx4 acc[8];
        #pragma unroll
        for (int nt = 0; nt < 8; ++nt) { acc[nt][0]=0.f; acc[nt][1]=0.f; acc[nt][2]=0.f; acc[nt][3]=0.f; }

        if (valid) {
            const int row = strip * 16 + m;
            short8 a[4];
            const float4* xr = reinterpret_cast<const float4*>(&x[(size_t)row * DIM]);
            #pragma unroll
            for (int ks = 0; ks < 4; ++ks) {
                const float4 f0 = xr[ks * 8 + q * 2];
                const float4 f1 = xr[ks * 8 + q * 2 + 1];
                short8 tt;
                tt[0] = (short)f2bf(f0.x); tt[1] = (short)f2bf(f0.y);
                tt[2] = (short)f2bf(f0.z); tt[3] = (short)f2bf(f0.w);
                tt[4] = (short)f2bf(f1.x); tt[5] = (short)f2bf(f1.y);
                tt[6] = (short)f2bf(f1.z); tt[7] = (short)f2bf(f1.w);
                a[ks] = tt;
            }
            const short8* w1f = (const short8*)smem;
            #pragma unroll
            for (int ks = 0; ks < 4; ++ks) {
                #pragma unroll
                for (int nt = 0; nt < 8; ++nt) {
                    const short8 bf = w1f[(ks * 8 + nt) * 64 + lane];
                    acc[nt] = __builtin_amdgcn_mfma_f32_16x16x32_bf16(a[ks], bf, acc[nt], 0, 0, 0);
                }
            }
        }
        __syncthreads();          // all waves done reading w1f -> reuse as stg

        // stage bf16 elements [64][136], then permuted coalesced writeout
        unsigned short* stg = (unsigned short*)smem;
        if (valid) {
            #pragma unroll
            for (int nt = 0; nt < 8; ++nt) {
                const float bb = bias[nt * 16 + m];
                #pragma unroll
                for (int i = 0; i < 4; ++i)
                    stg[(wave * 16 + q * 4 + i) * 136 + nt * 16 + m] = f2bf(acc[nt][i] + bb);
            }
        }
        __syncthreads();
        // support dword l of row r = (dim l) | (dim l+64)<<16
        #pragma unroll
        for (int k2 = 0; k2 < 8; ++k2) {
            const int pidx = t + k2 * 256;               // 2048 dword-pairs
            const int r  = pidx >> 5;
            const int l2 = pidx & 31;
            const unsigned lo0 = stg[r * 136 + 2 * l2];
            const unsigned lo1 = stg[r * 136 + 2 * l2 + 1];
            const unsigned hi0 = stg[r * 136 + 2 * l2 + 64];
            const unsigned hi1 = stg[r * 136 + 2 * l2 + 65];
            uint2 o;
            o.x = lo0 | (hi0 << 16);
            o.y = lo1 | (hi1 << 16);
            *reinterpret_cast<uint2*>(&support[((size_t)gb * 64 + r) * 64 + 2 * l2]) = o;
        }
    } else {
        // ---------------- pack W2 ----------------
        const int pb   = blockIdx.x - (EDGE_CHUNKS + GEMM_BLOCKS);  // 0..7
        const int s    = pb * 256 + t;
        const int lane = s & 63;
        const int nt   = (s >> 6) & 7;
        const int ks   = s >> 9;
        const int m    = lane & 15;
        const int q    = lane >> 4;
        const float4 f0 = *reinterpret_cast<const float4*>(&W2[(nt * 16 + m) * DIM + ks * 32 + q * 8]);
        const float4 f1 = *reinterpret_cast<const float4*>(&W2[(nt * 16 + m) * DIM + ks * 32 + q * 8 + 4]);
        unsigned short e[8];
        e[0] = f2bf(f0.x); e[1] = f2bf(f0.y); e[2] = f2bf(f0.z); e[3] = f2bf(f0.w);
        e[4] = f2bf(f1.x); e[5] = f2bf(f1.y); e[6] = f2bf(f1.z); e[7] = f2bf(f1.w);
        uint4 o;
        o.x = (unsigned)e[0] | ((unsigned)e[1] << 16);
        o.y = (unsigned)e[2] | ((unsigned)e[3] << 16);
        o.z = (unsigned)e[4] | ((unsigned)e[5] << 16);
        o.w = (unsigned)e[6] | ((unsigned)e[7] << 16);
        p2[s] = o;
    }
}

// ---------------------------------------------------------------------------
// Dispatch 2 (782 blocks, 256 thr): per 64-node bucket, SORT-FREE.
//  A: stream the bucket's edges; per edge, lane l loads support dword l
//     (dims l, l+64) and ds_add_f32 into agg[node][l], agg[node][64+l]
//     (banks l%32 -> 2-way, free). 8-deep software-pipelined.
//  B: GEMM2 from LDS agg (relu+cvt in fragment load) + bias + row L2-norm.
// LDS = 33.8 KB -> 4 blocks/CU, 16 waves/CU.
// ---------------------------------------------------------------------------
__global__ __launch_bounds__(256) void gather_gemm2(
    const unsigned int* __restrict__ sup, const int2* __restrict__ bucketed,
    const int* __restrict__ bcnt, const short8* __restrict__ Bp,
    const float* __restrict__ bias, float* __restrict__ out)
{
    __shared__ float aggf[64 * AGS];           // 33792 B

    const int b = blockIdx.x;
    const int t = threadIdx.x;
    int nE = bcnt[b];
    if (nE > BCAP) nE = BCAP;
    const int2* eb = bucketed + (size_t)b * BCAP;

    for (int i = t; i < 64 * AGS; i += 256) aggf[i] = 0.f;
    __syncthreads();

    const int w = t >> 6, lane = t & 63;
    // wave w handles edges e = w, w+4, w+8, ...
    const int nW = (nE > w) ? ((nE - w + 3) >> 2) : 0;
    int i = 0;
    if (nW >= 8) {
        int2 pc[8];
        #pragma unroll
        for (int k = 0; k < 8; ++k) pc[k] = eb[w + k * 4];
        for (; i + 16 <= nW; i += 8) {
            unsigned int u[8];
            #pragma unroll
            for (int k = 0; k < 8; ++k) u[k] = sup[(size_t)(pc[k].x & 0xFFFF) * 64 + lane];
            int2 pn[8];
            #pragma unroll
            for (int k = 0; k < 8; ++k) pn[k] = eb[w + (i + 8 + k) * 4];
            #pragma unroll
            for (int k = 0; k < 8; ++k) {
                const int   node = (pc[k].x >> 16) & 63;
                const float v    = __int_as_float(pc[k].y);
                atomicAdd(&aggf[node * AGS + lane],      __uint_as_float(u[k] << 16) * v);
                atomicAdd(&aggf[node * AGS + 64 + lane], __uint_as_float(u[k] & 0xffff0000u) * v);
            }
            #pragma unroll
            for (int k = 0; k < 8; ++k) pc[k] = pn[k];
        }
        {   // drain the group held in pc
            unsigned int u[8];
            #pragma unroll
            for (int k = 0; k < 8; ++k) u[k] = sup[(size_t)(pc[k].x & 0xFFFF) * 64 + lane];
            #pragma unroll
            for (int k = 0; k < 8; ++k) {
                const int   node = (pc[k].x >> 16) & 63;
                const float v    = __int_as_float(pc[k].y);
                atomicAdd(&aggf[node * AGS + lane],      __uint_as_float(u[k] << 16) * v);
                atomicAdd(&aggf[node * AGS + 64 + lane], __uint_as_float(u[k] & 0xffff0000u) * v);
            }
            i += 8;
        }
    }
    for (; i < nW; ++i) {
        const int2 p = eb[w + i * 4];
        const unsigned int u = sup[(size_t)(p.x & 0xFFFF) * 64 + lane];
        const int   node = (p.x >> 16) & 63;
        const float v    = __int_as_float(p.y);
        atomicAdd(&aggf[node * AGS + lane],      __uint_as_float(u << 16) * v);
        atomicAdd(&aggf[node * AGS + 64 + lane], __uint_as_float(u & 0xffff0000u) * v);
    }
    __syncthreads();

    // ---- GEMM2 + row L2-norm: wave w owns rows w*16..+16 ----
    const int row0 = b * 64 + w * 16;
    if (row0 >= N_NODES) return;               // bucket 781: waves 1-3 idle
    const int m = lane & 15;
    const int q = lane >> 4;

    short8 a[4];
    #pragma unroll
    for (int ks = 0; ks < 4; ++ks) {
        const float* ap = &aggf[(w * 16 + m) * AGS + ks * 32 + q * 8];
        short8 tt;
        #pragma unroll
        for (int j = 0; j < 8; ++j) tt[j] = (short)f2bf(fmaxf(ap[j], 0.f));
        a[ks] = tt;
    }

    floatx4 acc[8];
    #pragma unroll
    for (int nt = 0; nt < 8; ++nt) { acc[nt][0]=0.f; acc[nt][1]=0.f; acc[nt][2]=0.f; acc[nt][3]=0.f; }

    #pragma unroll
    for (int ks = 0; ks < 4; ++ks) {
        #pragma unroll
        for (int nt = 0; nt < 8; ++nt) {
            const short8 bf = Bp[(ks * 8 + nt) * 64 + lane];
            acc[nt] = __builtin_amdgcn_mfma_f32_16x16x32_bf16(a[ks], bf, acc[nt], 0, 0, 0);
        }
    }

    #pragma unroll
    for (int nt = 0; nt < 8; ++nt) {
        const float bb = bias[nt * 16 + m];
        #pragma unroll
        for (int i2 = 0; i2 < 4; ++i2) acc[nt][i2] += bb;
    }

    float sq[4] = {0.f, 0.f, 0.f, 0.f};
    #pragma unroll
    for (int nt = 0; nt < 8; ++nt)
        #pragma unroll
        for (int i2 = 0; i2 < 4; ++i2) sq[i2] += acc[nt][i2] * acc[nt][i2];
    #pragma unroll
    for (int i2 = 0; i2 < 4; ++i2) {
        #pragma unroll
        for (int mask = 1; mask < 16; mask <<= 1)
            sq[i2] += __shfl_xor(sq[i2], mask);
        sq[i2] = 1.0f / sqrtf(sq[i2]);
    }

    #pragma unroll
    for (int nt = 0; nt < 8; ++nt) {
        #pragma unroll
        for (int i2 = 0; i2 < 4; ++i2) {
            const int r = row0 + q * 4 + i2;
            out[(size_t)r * DIM + nt * 16 + m] = acc[nt][i2] * sq[i2];
        }
    }
}

// ---------------------------------------------------------------------------
extern "C" void kernel_launch(void* const* d_in, const int* in_sizes, int n_in,
                              void* d_out, int out_size, void* d_ws, size_t ws_size,
                              hipStream_t stream) {
    const float* x    = (const float*)d_in[0];
    const float* vals = (const float*)d_in[1];
    const float* W_gc = (const float*)d_in[2];
    const float* b_gc = (const float*)d_in[3];
    const float* W2   = (const float*)d_in[4];
    const float* b2   = (const float*)d_in[5];
    const int*   src  = (const int*)d_in[6];
    const int*   dst  = (const int*)d_in[7];

    float* out = (float*)d_out;

    // ws layout (16B-aligned)
    const size_t SUP_B = (size_t)SUP_ROWS * DIM * 2;     // 12,812,288 (bf16, permuted dwords)
    const size_t BUK_B = (size_t)N_BKT * BCAP * 8;       // 9,609,216
    char* wsb = (char*)d_ws;
    unsigned int* support = (unsigned int*)wsb;
    int2*  bucketed = (int2*)(wsb + SUP_B);
    int*   bcnt     = (int*)(wsb + SUP_B + BUK_B);
    uint4* pw2      = (uint4*)(wsb + SUP_B + BUK_B + 4096);

    // 0. zero bucket counters (graph-capturable async memset, 3.2 KB)
    hipMemsetAsync(bcnt, 0, 800 * sizeof(int), stream);

    // 1. scatter || GEMM1 (inline W1 pack, permuted support) || W2 pack
    fused1<<<D1_BLOCKS, 256, 0, stream>>>(
        x, W_gc, b_gc, W2, src, dst, vals, support, bcnt, bucketed, pw2);

    // 2. per-bucket sort-free LDS-atomic aggregate + GEMM2 + norm
    gather_gemm2<<<N_BKT, 256, 0, stream>>>(
        support, bucketed, bcnt, (const short8*)pw2, b2, out);
}

// Round 5
// 156.845 us; speedup vs baseline: 5.0526x; 5.0526x over previous
//
#include <hip/hip_runtime.h>
#include <hip/hip_bf16.h>

#define N_NODES 50000
#define N_EDGES 800000
#define DIM     128
#define N_STRIPS (N_NODES / 16)               // 3125 exact: 16-row strips
#define N_BKT    782                          // bucket = dst >> 6 (64 nodes/bucket)
#define CHUNK_E  4096                         // edges per scatter chunk
#define EDGE_CHUNKS 196                       // 195*4096 + 1280
#define BCAP     1536                         // bucket region cap (mean 1024, 16 sigma)
#define EBUF_CAP 1408                         // LDS sorted-edge cap (mean 1024, 12 sigma)
#define GEMM_BLOCKS 782                       // ceil(3125/4)
#define D1_BLOCKS (EDGE_CHUNKS + GEMM_BLOCKS + 8)  // 986
#define SUP_ROWS 50048                        // support rows incl. tail-strip slack
#define AGS      68                           // agg LDS row stride (dwords)

typedef short short8 __attribute__((ext_vector_type(8)));
typedef float floatx4 __attribute__((ext_vector_type(4)));

// fp32 -> bf16 (RNE) bit pattern
__device__ inline unsigned short f2bf(float f) {
    __hip_bfloat16 h = __float2bfloat16(f);
    return *reinterpret_cast<unsigned short*>(&h);
}

__device__ inline uint4 pack8_relu(const float a[8]) {
    uint4 o;
    o.x = (unsigned)f2bf(fmaxf(a[0],0.f)) | ((unsigned)f2bf(fmaxf(a[1],0.f)) << 16);
    o.y = (unsigned)f2bf(fmaxf(a[2],0.f)) | ((unsigned)f2bf(fmaxf(a[3],0.f)) << 16);
    o.z = (unsigned)f2bf(fmaxf(a[4],0.f)) | ((unsigned)f2bf(fmaxf(a[5],0.f)) << 16);
    o.w = (unsigned)f2bf(fmaxf(a[6],0.f)) | ((unsigned)f2bf(fmaxf(a[7],0.f)) << 16);
    return o;
}

// ---------------------------------------------------------------------------
// Dispatch 1 (986 blocks):
//  [0,196):    bucket scatter via atomic range reservation
//  [196,978):  GEMM1: inline W1->LDS fragment pack, MFMA, LDS-staged
//              coalesced uint4 writeout of bf16 support (standard layout:
//              dword l of row r = dims 2l | 2l+1).
//  [978,986):  pack W2 (B[k][n]=W2[n][k]) -> pw2 (consumed by dispatch 2)
// Shared: 32 KB overlay (scatter: bh/rcur; GEMM1: W1 frags, then stg).
// NO FP atomics anywhere (round-4 lesson: LDS f32 atomicAdd = CAS loop).
// ---------------------------------------------------------------------------
__global__ __launch_bounds__(256) void fused1(
    const float* __restrict__ x, const float* __restrict__ W1,
    const float* __restrict__ bias, const float* __restrict__ W2,
    const int* __restrict__ src, const int* __restrict__ dst,
    const float* __restrict__ vals,
    unsigned short* __restrict__ support, int* __restrict__ bcnt,
    int2* __restrict__ bucketed, uint4* __restrict__ p2)
{
    __shared__ __align__(16) char smem[32768];
    const int t = threadIdx.x;

    if (blockIdx.x < EDGE_CHUNKS) {
        // ---------------- bucket scatter ----------------
        int* bh   = (int*)smem;          // [800]
        int* rcur = (int*)smem + 800;    // [800]
        const int chunk = blockIdx.x;
        for (int i = t; i < 800; i += 256) bh[i] = 0;
        __syncthreads();
        const int base   = chunk * CHUNK_E;
        const int navail = min(CHUNK_E, N_EDGES - base); // 4096 or 1280; %4==0
        const int4* d4 = reinterpret_cast<const int4*>(dst + base);
        #pragma unroll
        for (int i = 0; i < 4; ++i) {
            const int j = t + i * 256;
            if (j * 4 < navail) {
                const int4 d = d4[j];
                atomicAdd(&bh[d.x >> 6], 1);
                atomicAdd(&bh[d.y >> 6], 1);
                atomicAdd(&bh[d.z >> 6], 1);
                atomicAdd(&bh[d.w >> 6], 1);
            }
        }
        __syncthreads();
        for (int b = t; b < N_BKT; b += 256)
            rcur[b] = b * BCAP + atomicAdd(&bcnt[b], bh[b]);
        __syncthreads();
        const int4*   s4 = reinterpret_cast<const int4*>(src + base);
        const float4* v4 = reinterpret_cast<const float4*>(vals + base);
        #pragma unroll
        for (int i = 0; i < 4; ++i) {
            const int j = t + i * 256;
            if (j * 4 < navail) {
                const int4   s = s4[j];
                const int4   d = d4[j];
                const float4 v = v4[j];
                int p;
                p = atomicAdd(&rcur[d.x >> 6], 1);
                bucketed[p] = make_int2((s.x & 0xFFFF) | ((d.x & 63) << 16), __float_as_int(v.x));
                p = atomicAdd(&rcur[d.y >> 6], 1);
                bucketed[p] = make_int2((s.y & 0xFFFF) | ((d.y & 63) << 16), __float_as_int(v.y));
                p = atomicAdd(&rcur[d.z >> 6], 1);
                bucketed[p] = make_int2((s.z & 0xFFFF) | ((d.z & 63) << 16), __float_as_int(v.z));
                p = atomicAdd(&rcur[d.w >> 6], 1);
                bucketed[p] = make_int2((s.w & 0xFFFF) | ((d.w & 63) << 16), __float_as_int(v.w));
            }
        }
    } else if (blockIdx.x < EDGE_CHUNKS + GEMM_BLOCKS) {
        // ---------------- GEMM1 ----------------
        const int gb    = blockIdx.x - EDGE_CHUNKS;      // 0..781
        const int wave  = t >> 6;
        const int lane  = t & 63;
        const int strip = gb * 4 + wave;
        const int m = lane & 15;
        const int q = lane >> 4;
        const bool valid = strip < N_STRIPS;             // block 781: waves 1-3 idle

        // cooperative W1 -> LDS fragment pack (coalesced global float4 reads)
        unsigned short* w1e = (unsigned short*)smem;     // element view: slot*8+j
        #pragma unroll
        for (int i = 0; i < 16; ++i) {
            const int f4 = t + i * 256;                  // 4096 float4 = 16384 elems
            const float4 v = reinterpret_cast<const float4*>(W1)[f4];
            const float vv[4] = {v.x, v.y, v.z, v.w};
            const int e0 = f4 * 4;
            #pragma unroll
            for (int j = 0; j < 4; ++j) {
                const int k = (e0 + j) >> 7, n = (e0 + j) & 127;
                const int ks = k >> 5, qq = (k >> 3) & 3, jj = k & 7;
                const int nt = n >> 4, mm = n & 15;
                w1e[((ks * 8 + nt) * 64 + qq * 16 + mm) * 8 + jj] = f2bf(vv[j]);
            }
        }
        __syncthreads();

        floatx4 acc[8];
        #pragma unroll
        for (int nt = 0; nt < 8; ++nt) { acc[nt][0]=0.f; acc[nt][1]=0.f; acc[nt][2]=0.f; acc[nt][3]=0.f; }

        if (valid) {
            const int row = strip * 16 + m;
            short8 a[4];
            const float4* xr = reinterpret_cast<const float4*>(&x[(size_t)row * DIM]);
            #pragma unroll
            for (int ks = 0; ks < 4; ++ks) {
                const float4 f0 = xr[ks * 8 + q * 2];
                const float4 f1 = xr[ks * 8 + q * 2 + 1];
                short8 tt;
                tt[0] = (short)f2bf(f0.x); tt[1] = (short)f2bf(f0.y);
                tt[2] = (short)f2bf(f0.z); tt[3] = (short)f2bf(f0.w);
                tt[4] = (short)f2bf(f1.x); tt[5] = (short)f2bf(f1.y);
                tt[6] = (short)f2bf(f1.z); tt[7] = (short)f2bf(f1.w);
                a[ks] = tt;
            }
            const short8* w1f = (const short8*)smem;
            #pragma unroll
            for (int ks = 0; ks < 4; ++ks) {
                #pragma unroll
                for (int nt = 0; nt < 8; ++nt) {
                    const short8 bf = w1f[(ks * 8 + nt) * 64 + lane];
                    acc[nt] = __builtin_amdgcn_mfma_f32_16x16x32_bf16(a[ks], bf, acc[nt], 0, 0, 0);
                }
            }
        }
        __syncthreads();          // all waves done reading w1f -> reuse as stg

        // stage bf16 elements [64][136], then coalesced uint4 writeout
        unsigned short* stg = (unsigned short*)smem;
        if (valid) {
            #pragma unroll
            for (int nt = 0; nt < 8; ++nt) {
                const float bb = bias[nt * 16 + m];
                #pragma unroll
                for (int i = 0; i < 4; ++i)
                    stg[(wave * 16 + q * 4 + i) * 136 + nt * 16 + m] = f2bf(acc[nt][i] + bb);
            }
        }
        __syncthreads();
        const size_t rbase = (size_t)gb * 64;
        #pragma unroll
        for (int k2 = 0; k2 < 4; ++k2) {
            const int chunk2 = t + k2 * 256;             // 1024 uint4 pieces
            const int lrow  = chunk2 >> 4;
            const int piece = chunk2 & 15;
            const uint4 v = *reinterpret_cast<const uint4*>(&stg[lrow * 136 + piece * 8]);
            *reinterpret_cast<uint4*>(&support[(rbase + lrow) * DIM + piece * 8]) = v;
        }
    } else {
        // ---------------- pack W2 ----------------
        const int pb   = blockIdx.x - (EDGE_CHUNKS + GEMM_BLOCKS);  // 0..7
        const int s    = pb * 256 + t;
        const int lane = s & 63;
        const int nt   = (s >> 6) & 7;
        const int ks   = s >> 9;
        const int m    = lane & 15;
        const int q    = lane >> 4;
        const float4 f0 = *reinterpret_cast<const float4*>(&W2[(nt * 16 + m) * DIM + ks * 32 + q * 8]);
        const float4 f1 = *reinterpret_cast<const float4*>(&W2[(nt * 16 + m) * DIM + ks * 32 + q * 8 + 4]);
        unsigned short e[8];
        e[0] = f2bf(f0.x); e[1] = f2bf(f0.y); e[2] = f2bf(f0.z); e[3] = f2bf(f0.w);
        e[4] = f2bf(f1.x); e[5] = f2bf(f1.y); e[6] = f2bf(f1.z); e[7] = f2bf(f1.w);
        uint4 o;
        o.x = (unsigned)e[0] | ((unsigned)e[1] << 16);
        o.y = (unsigned)e[2] | ((unsigned)e[3] << 16);
        o.z = (unsigned)e[4] | ((unsigned)e[5] << 16);
        o.w = (unsigned)e[6] | ((unsigned)e[7] << 16);
        p2[s] = o;
    }
}

// ---------------------------------------------------------------------------
// Dispatch 2: one block (512 thr, 8 waves) per 64-node bucket.
//  A: counting-sort the bucket's edges into LDS (ebuf)            [11 KB]
//  B: gather: wave w owns nodes w*8..+8; 4 edges per VMEM instr (lane
//     l>>4 picks edge, lane&15 picks uint4 dim-block), x4 unrolled ->
//     ~16 outstanding loads/wave; 8 waves/block x ~3 blocks/CU = ~24
//     waves/CU of MLP (2x round-2). shfl-reduce over lane quarters,
//     relu, bf16 -> agg LDS.                                      [17 KB]
//  C: GEMM2 (MFMA, waves 0-3) + bias + row L2-norm from LDS agg.
// 29.4 KB LDS; occupancy = 4 blocks/CU (wave-slot limited).
// ---------------------------------------------------------------------------
__global__ __launch_bounds__(512) void agg_gemm2(
    const unsigned int* __restrict__ sup, const int2* __restrict__ bucketed,
    const int* __restrict__ bcnt, const short8* __restrict__ Bp,
    const float* __restrict__ bias, float* __restrict__ out)
{
    __shared__ int2 ebuf[EBUF_CAP];            // 11264 B
    __shared__ unsigned int agg[64 * AGS];     // 17408 B
    __shared__ int cnt[64];
    __shared__ int coff[64];
    __shared__ int cur[64];

    const int b = blockIdx.x;
    const int t = threadIdx.x;
    int nE = bcnt[b];
    if (nE > EBUF_CAP) nE = EBUF_CAP;          // 12-sigma guard, never taken
    const int base = b * BCAP;

    // ---- phase A: counting sort by dst&63 into ebuf ----
    if (t < 64) cnt[t] = 0;
    __syncthreads();
    for (int i = t; i < nE; i += 512)
        atomicAdd(&cnt[(bucketed[base + i].x >> 16) & 63], 1);
    __syncthreads();
    if (t < 64) coff[t] = cnt[t];
    __syncthreads();
    for (int off = 1; off < 64; off <<= 1) {
        int u = 0;
        if (t < 64 && t >= off) u = coff[t - off];
        __syncthreads();
        if (t < 64 && t >= off) coff[t] += u;
        __syncthreads();
    }
    if (t < 64) cur[t] = coff[t] - cnt[t];     // exclusive prefix
    __syncthreads();
    for (int i = t; i < nE; i += 512) {
        const int2 e = bucketed[base + i];
        const int  n = (e.x >> 16) & 63;
        const int  p = atomicAdd(&cur[n], 1);
        ebuf[p] = e;
    }
    __syncthreads();

    // ---- phase B: wave w -> nodes w*8..+8; 4 edges per VMEM inst ----
    const int w    = t >> 6;
    const int lane = t & 63;
    const int g    = lane >> 4;                // edge sub-slot 0..3
    const int dl   = lane & 15;                // dim block: dims 8*dl..+8

    for (int nl = w * 8; nl < w * 8 + 8; ++nl) {
        const int end = cur[nl];               // = excl + cnt after scatter
        const int c   = cnt[nl];
        const int beg = end - c;
        float acc[8];
        #pragma unroll
        for (int k = 0; k < 8; ++k) acc[k] = 0.f;

        const int nI = (c + 3) >> 2;           // instructions (4 edges each)
        auto step = [&](int it) {
            const int  idx = beg + it * 4 + g;
            const bool vld = idx < end;
            const int2 e   = ebuf[vld ? idx : beg];
            const float val = vld ? __int_as_float(e.y) : 0.f;
            const uint4 u = *reinterpret_cast<const uint4*>(
                &sup[(size_t)(e.x & 0xFFFF) * 64 + dl * 4]);
            acc[0] += __uint_as_float(u.x << 16)          * val;
            acc[1] += __uint_as_float(u.x & 0xffff0000u)  * val;
            acc[2] += __uint_as_float(u.y << 16)          * val;
            acc[3] += __uint_as_float(u.y & 0xffff0000u)  * val;
            acc[4] += __uint_as_float(u.z << 16)          * val;
            acc[5] += __uint_as_float(u.z & 0xffff0000u)  * val;
            acc[6] += __uint_as_float(u.w << 16)          * val;
            acc[7] += __uint_as_float(u.w & 0xffff0000u)  * val;
        };
        int it = 0;
        for (; it + 3 < nI; it += 4) { step(it); step(it+1); step(it+2); step(it+3); }
        for (; it < nI; ++it) step(it);

        // combine partial sums across the 4 lane-quarters (g dimension)
        #pragma unroll
        for (int k = 0; k < 8; ++k) {
            acc[k] += __shfl_xor(acc[k], 16);
            acc[k] += __shfl_xor(acc[k], 32);
        }
        if (lane < 16) {                       // lanes 0..15 write the row
            *reinterpret_cast<uint4*>(&agg[nl * AGS + dl * 4]) = pack8_relu(acc);
        }
    }
    __syncthreads();

    // ---- phase C: out = rownorm(agg @ W2^T + b2), waves 0-3 own strips ----
    if (w >= 4) return;
    const int row0 = b * 64 + w * 16;
    if (row0 >= N_NODES) return;               // bucket 781: strips 1-3 idle
    const int m = lane & 15;
    const int q = lane >> 4;

    short8 a[4];
    #pragma unroll
    for (int ks = 0; ks < 4; ++ks) {
        const uint4 t4 = *reinterpret_cast<const uint4*>(&agg[(w * 16 + m) * AGS + ks * 16 + q * 4]);
        a[ks] = *reinterpret_cast<const short8*>(&t4);
    }

    floatx4 acc[8];
    #pragma unroll
    for (int nt = 0; nt < 8; ++nt) { acc[nt][0]=0.f; acc[nt][1]=0.f; acc[nt][2]=0.f; acc[nt][3]=0.f; }

    #pragma unroll
    for (int ks = 0; ks < 4; ++ks) {
        #pragma unroll
        for (int nt = 0; nt < 8; ++nt) {
            const short8 bf = Bp[(ks * 8 + nt) * 64 + lane];
            acc[nt] = __builtin_amdgcn_mfma_f32_16x16x32_bf16(a[ks], bf, acc[nt], 0, 0, 0);
        }
    }

    #pragma unroll
    for (int nt = 0; nt < 8; ++nt) {
        const float bb = bias[nt * 16 + m];
        #pragma unroll
        for (int i = 0; i < 4; ++i) acc[nt][i] += bb;
    }

    float sq[4] = {0.f, 0.f, 0.f, 0.f};
    #pragma unroll
    for (int nt = 0; nt < 8; ++nt)
        #pragma unroll
        for (int i = 0; i < 4; ++i) sq[i] += acc[nt][i] * acc[nt][i];
    #pragma unroll
    for (int i = 0; i < 4; ++i) {
        #pragma unroll
        for (int mask = 1; mask < 16; mask <<= 1)
            sq[i] += __shfl_xor(sq[i], mask);
        sq[i] = 1.0f / sqrtf(sq[i]);
    }

    #pragma unroll
    for (int nt = 0; nt < 8; ++nt) {
        #pragma unroll
        for (int i = 0; i < 4; ++i) {
            const int r = row0 + q * 4 + i;
            out[(size_t)r * DIM + nt * 16 + m] = acc[nt][i] * sq[i];
        }
    }
}

// ---------------------------------------------------------------------------
extern "C" void kernel_launch(void* const* d_in, const int* in_sizes, int n_in,
                              void* d_out, int out_size, void* d_ws, size_t ws_size,
                              hipStream_t stream) {
    const float* x    = (const float*)d_in[0];
    const float* vals = (const float*)d_in[1];
    const float* W_gc = (const float*)d_in[2];
    const float* b_gc = (const float*)d_in[3];
    const float* W2   = (const float*)d_in[4];
    const float* b2   = (const float*)d_in[5];
    const int*   src  = (const int*)d_in[6];
    const int*   dst  = (const int*)d_in[7];

    float* out = (float*)d_out;

    // ws layout (16B-aligned)
    const size_t SUP_B = (size_t)SUP_ROWS * DIM * 2;     // 12,812,288 (bf16)
    const size_t BUK_B = (size_t)N_BKT * BCAP * 8;       // 9,609,216
    char* wsb = (char*)d_ws;
    unsigned short* support = (unsigned short*)wsb;
    int2*  bucketed = (int2*)(wsb + SUP_B);
    int*   bcnt     = (int*)(wsb + SUP_B + BUK_B);
    uint4* pw2      = (uint4*)(wsb + SUP_B + BUK_B + 4096);

    // 0. zero bucket counters (graph-capturable async memset, 3.2 KB)
    hipMemsetAsync(bcnt, 0, 800 * sizeof(int), stream);

    // 1. scatter || GEMM1 (inline W1 pack) || W2 pack
    fused1<<<D1_BLOCKS, 256, 0, stream>>>(
        x, W_gc, b_gc, W2, src, dst, vals, support, bcnt, bucketed, pw2);

    // 2. per-bucket: LDS counting sort -> 8-wave register gather -> GEMM2 + norm
    agg_gemm2<<<N_BKT, 512, 0, stream>>>(
        (const unsigned int*)support, bucketed, bcnt, (const short8*)pw2, b2, out);
}

// Round 6
// 153.658 us; speedup vs baseline: 5.1574x; 1.0207x over previous
//
#include <hip/hip_runtime.h>
#include <hip/hip_bf16.h>

#define N_NODES 50000
#define N_EDGES 800000
#define DIM     128
#define N_BKT    782                          // bucket = dst >> 6 (64 nodes/bucket)
#define CHUNK_E  4096                         // edges per scatter chunk
#define EDGE_CHUNKS 196                       // 195*4096 + 1280
#define BCAP     1536                         // bucket region cap (mean 1024, 16 sigma)
#define EBUF_CAP 1408                         // LDS sorted-edge cap (mean 1024, 12 sigma)
#define CONV_BLOCKS 128
#define D1_BLOCKS (EDGE_CHUNKS + CONV_BLOCKS + 16)  // 340
#define AGS      68                           // agg LDS row stride (dwords)

typedef short short8 __attribute__((ext_vector_type(8)));
typedef float floatx4 __attribute__((ext_vector_type(4)));

// fp32 -> bf16 (RNE) bit pattern
__device__ inline unsigned short f2bf(float f) {
    __hip_bfloat16 h = __float2bfloat16(f);
    return *reinterpret_cast<unsigned short*>(&h);
}

__device__ inline uint4 pack8(const float a[8]) {
    uint4 o;
    o.x = (unsigned)f2bf(a[0]) | ((unsigned)f2bf(a[1]) << 16);
    o.y = (unsigned)f2bf(a[2]) | ((unsigned)f2bf(a[3]) << 16);
    o.z = (unsigned)f2bf(a[4]) | ((unsigned)f2bf(a[5]) << 16);
    o.w = (unsigned)f2bf(a[6]) | ((unsigned)f2bf(a[7]) << 16);
    return o;
}

// ---------------------------------------------------------------------------
// Dispatch 1 (340 blocks) — NO GEMM here (linearity: agg commutes with W1):
//  [0,196):   bucket scatter via atomic range reservation
//  [196,324): x f32 -> bf16 convert (xb, dword l of row = dims 2l|2l+1)
//  [324,332): pack W1 fragments (B[k][n] = W1[k][n]) -> pw1
//  [332,340): pack W2 fragments (B[k][n] = W2[n][k]) -> pw2
// ---------------------------------------------------------------------------
__global__ __launch_bounds__(256) void fused1(
    const float* __restrict__ x, const float* __restrict__ W1,
    const float* __restrict__ W2,
    const int* __restrict__ src, const int* __restrict__ dst,
    const float* __restrict__ vals,
    unsigned int* __restrict__ xb, int* __restrict__ bcnt,
    int2* __restrict__ bucketed,
    uint4* __restrict__ p1, uint4* __restrict__ p2)
{
    __shared__ int bh[800];
    __shared__ int rcur[800];
    const int t = threadIdx.x;

    if (blockIdx.x < EDGE_CHUNKS) {
        // ---------------- bucket scatter ----------------
        const int chunk = blockIdx.x;
        for (int i = t; i < 800; i += 256) bh[i] = 0;
        __syncthreads();
        const int base   = chunk * CHUNK_E;
        const int navail = min(CHUNK_E, N_EDGES - base); // 4096 or 1280; %4==0
        const int4* d4 = reinterpret_cast<const int4*>(dst + base);
        #pragma unroll
        for (int i = 0; i < 4; ++i) {
            const int j = t + i * 256;
            if (j * 4 < navail) {
                const int4 d = d4[j];
                atomicAdd(&bh[d.x >> 6], 1);
                atomicAdd(&bh[d.y >> 6], 1);
                atomicAdd(&bh[d.z >> 6], 1);
                atomicAdd(&bh[d.w >> 6], 1);
            }
        }
        __syncthreads();
        for (int b = t; b < N_BKT; b += 256)
            rcur[b] = b * BCAP + atomicAdd(&bcnt[b], bh[b]);
        __syncthreads();
        const int4*   s4 = reinterpret_cast<const int4*>(src + base);
        const float4* v4 = reinterpret_cast<const float4*>(vals + base);
        #pragma unroll
        for (int i = 0; i < 4; ++i) {
            const int j = t + i * 256;
            if (j * 4 < navail) {
                const int4   s = s4[j];
                const int4   d = d4[j];
                const float4 v = v4[j];
                int p;
                p = atomicAdd(&rcur[d.x >> 6], 1);
                bucketed[p] = make_int2((s.x & 0xFFFF) | ((d.x & 63) << 16), __float_as_int(v.x));
                p = atomicAdd(&rcur[d.y >> 6], 1);
                bucketed[p] = make_int2((s.y & 0xFFFF) | ((d.y & 63) << 16), __float_as_int(v.y));
                p = atomicAdd(&rcur[d.z >> 6], 1);
                bucketed[p] = make_int2((s.z & 0xFFFF) | ((d.z & 63) << 16), __float_as_int(v.z));
                p = atomicAdd(&rcur[d.w >> 6], 1);
                bucketed[p] = make_int2((s.w & 0xFFFF) | ((d.w & 63) << 16), __float_as_int(v.w));
            }
        }
    } else if (blockIdx.x < EDGE_CHUNKS + CONV_BLOCKS) {
        // ---------------- x -> bf16 convert (streaming) ----------------
        const int cb = blockIdx.x - EDGE_CHUNKS;
        const float4* x4 = reinterpret_cast<const float4*>(x);
        uint2* xb2 = reinterpret_cast<uint2*>(xb);
        for (int i = cb * 256 + t; i < N_NODES * DIM / 4; i += CONV_BLOCKS * 256) {
            const float4 f = x4[i];
            uint2 o;
            o.x = (unsigned)f2bf(f.x) | ((unsigned)f2bf(f.y) << 16);
            o.y = (unsigned)f2bf(f.z) | ((unsigned)f2bf(f.w) << 16);
            xb2[i] = o;
        }
    } else if (blockIdx.x < EDGE_CHUNKS + CONV_BLOCKS + 8) {
        // ---------------- pack W1: B[k][n] = W1[k][n] ----------------
        const int pb   = blockIdx.x - (EDGE_CHUNKS + CONV_BLOCKS);  // 0..7
        const int s    = pb * 256 + t;                   // 0..2047
        const int lane = s & 63;
        const int nt   = (s >> 6) & 7;
        const int ks   = s >> 9;
        const int m    = lane & 15;
        const int q    = lane >> 4;
        unsigned short e[8];
        #pragma unroll
        for (int j = 0; j < 8; ++j)
            e[j] = f2bf(W1[(ks * 32 + q * 8 + j) * DIM + nt * 16 + m]);
        uint4 o;
        o.x = (unsigned)e[0] | ((unsigned)e[1] << 16);
        o.y = (unsigned)e[2] | ((unsigned)e[3] << 16);
        o.z = (unsigned)e[4] | ((unsigned)e[5] << 16);
        o.w = (unsigned)e[6] | ((unsigned)e[7] << 16);
        p1[s] = o;
    } else {
        // ---------------- pack W2: B[k][n] = W2[n][k] ----------------
        const int pb   = blockIdx.x - (EDGE_CHUNKS + CONV_BLOCKS + 8); // 0..7
        const int s    = pb * 256 + t;
        const int lane = s & 63;
        const int nt   = (s >> 6) & 7;
        const int ks   = s >> 9;
        const int m    = lane & 15;
        const int q    = lane >> 4;
        const float4 f0 = *reinterpret_cast<const float4*>(&W2[(nt * 16 + m) * DIM + ks * 32 + q * 8]);
        const float4 f1 = *reinterpret_cast<const float4*>(&W2[(nt * 16 + m) * DIM + ks * 32 + q * 8 + 4]);
        unsigned short e[8];
        e[0] = f2bf(f0.x); e[1] = f2bf(f0.y); e[2] = f2bf(f0.z); e[3] = f2bf(f0.w);
        e[4] = f2bf(f1.x); e[5] = f2bf(f1.y); e[6] = f2bf(f1.z); e[7] = f2bf(f1.w);
        uint4 o;
        o.x = (unsigned)e[0] | ((unsigned)e[1] << 16);
        o.y = (unsigned)e[2] | ((unsigned)e[3] << 16);
        o.z = (unsigned)e[4] | ((unsigned)e[5] << 16);
        o.w = (unsigned)e[6] | ((unsigned)e[7] << 16);
        p2[s] = o;
    }
}

// ---------------------------------------------------------------------------
// Dispatch 2: one block (512 thr, 8 waves) per 64-node bucket.
//  A: counting-sort the bucket's edges into LDS (ebuf)
//  B: gather RAW bf16 x rows: wave w owns nodes w*8..+8; 4 edges per VMEM
//     instr; also accumulates sumval per node. shfl-reduce, bf16 -> agg LDS.
//  C1 (waves 0-3): GEMM1 from agg: out1 = aggx @ W1 + sumval*b_gc; relu;
//     bf16 back into agg (in-place, strip-local).
//  C2 (waves 0-3): GEMM2: out = rownorm(relu1 @ W2^T + b2).
// LDS ~29.7 KB. No FP atomics anywhere.
// ---------------------------------------------------------------------------
__global__ __launch_bounds__(512) void agg_gemms(
    const unsigned int* __restrict__ xb, const int2* __restrict__ bucketed,
    const int* __restrict__ bcnt,
    const short8* __restrict__ Bp1, const short8* __restrict__ Bp2,
    const float* __restrict__ bias1, const float* __restrict__ bias2,
    float* __restrict__ out)
{
    __shared__ int2 ebuf[EBUF_CAP];            // 11264 B
    __shared__ unsigned int agg[64 * AGS];     // 17408 B
    __shared__ float sv[64];
    __shared__ int cnt[64];
    __shared__ int coff[64];
    __shared__ int cur[64];

    const int b = blockIdx.x;
    const int t = threadIdx.x;
    int nE = bcnt[b];
    if (nE > EBUF_CAP) nE = EBUF_CAP;          // 12-sigma guard, never taken
    const int base = b * BCAP;

    // ---- phase A: counting sort by dst&63 into ebuf ----
    if (t < 64) cnt[t] = 0;
    __syncthreads();
    for (int i = t; i < nE; i += 512)
        atomicAdd(&cnt[(bucketed[base + i].x >> 16) & 63], 1);
    __syncthreads();
    if (t < 64) coff[t] = cnt[t];
    __syncthreads();
    for (int off = 1; off < 64; off <<= 1) {
        int u = 0;
        if (t < 64 && t >= off) u = coff[t - off];
        __syncthreads();
        if (t < 64 && t >= off) coff[t] += u;
        __syncthreads();
    }
    if (t < 64) cur[t] = coff[t] - cnt[t];     // exclusive prefix
    __syncthreads();
    for (int i = t; i < nE; i += 512) {
        const int2 e = bucketed[base + i];
        const int  n = (e.x >> 16) & 63;
        const int  p = atomicAdd(&cur[n], 1);
        ebuf[p] = e;
    }
    __syncthreads();

    // ---- phase B: wave w -> nodes w*8..+8; gather xb rows + sumval ----
    const int w    = t >> 6;
    const int lane = t & 63;
    const int g    = lane >> 4;                // edge sub-slot 0..3
    const int dl   = lane & 15;                // dim block: dims 8*dl..+8

    for (int nl = w * 8; nl < w * 8 + 8; ++nl) {
        const int end = cur[nl];               // = excl + cnt after scatter
        const int c   = cnt[nl];
        const int beg = end - c;
        float acc[8];
        #pragma unroll
        for (int k = 0; k < 8; ++k) acc[k] = 0.f;
        float sval = 0.f;

        const int nI = (c + 3) >> 2;           // instructions (4 edges each)
        auto step = [&](int it) {
            const int  idx = beg + it * 4 + g;
            const bool vld = idx < end;
            const int2 e   = ebuf[vld ? idx : beg];
            const float val = vld ? __int_as_float(e.y) : 0.f;
            const uint4 u = *reinterpret_cast<const uint4*>(
                &xb[(size_t)(e.x & 0xFFFF) * 64 + dl * 4]);
            sval += val;
            acc[0] += __uint_as_float(u.x << 16)          * val;
            acc[1] += __uint_as_float(u.x & 0xffff0000u)  * val;
            acc[2] += __uint_as_float(u.y << 16)          * val;
            acc[3] += __uint_as_float(u.y & 0xffff0000u)  * val;
            acc[4] += __uint_as_float(u.z << 16)          * val;
            acc[5] += __uint_as_float(u.z & 0xffff0000u)  * val;
            acc[6] += __uint_as_float(u.w << 16)          * val;
            acc[7] += __uint_as_float(u.w & 0xffff0000u)  * val;
        };
        int it = 0;
        for (; it + 3 < nI; it += 4) { step(it); step(it+1); step(it+2); step(it+3); }
        for (; it < nI; ++it) step(it);

        // combine partial sums across the 4 lane-quarters (g dimension)
        #pragma unroll
        for (int k = 0; k < 8; ++k) {
            acc[k] += __shfl_xor(acc[k], 16);
            acc[k] += __shfl_xor(acc[k], 32);
        }
        sval += __shfl_xor(sval, 16);
        sval += __shfl_xor(sval, 32);
        if (lane == 0) sv[nl] = sval;
        if (lane < 16) {                       // lanes 0..15 write the row (NO relu)
            *reinterpret_cast<uint4*>(&agg[nl * AGS + dl * 4]) = pack8(acc);
        }
    }
    __syncthreads();

    // ---- phase C1 (waves 0-3): GEMM1 + sumval*b1, relu, bf16 -> agg ----
    const bool act = (w < 4) && (b * 64 + w * 16 < N_NODES);  // bucket 781 tail
    const int m = lane & 15;
    const int q = lane >> 4;
    unsigned short* aggs = reinterpret_cast<unsigned short*>(agg);

    if (act) {
        short8 a[4];
        #pragma unroll
        for (int ks = 0; ks < 4; ++ks) {
            const uint4 t4 = *reinterpret_cast<const uint4*>(&agg[(w * 16 + m) * AGS + ks * 16 + q * 4]);
            a[ks] = *reinterpret_cast<const short8*>(&t4);
        }
        floatx4 acc[8];
        #pragma unroll
        for (int nt = 0; nt < 8; ++nt) { acc[nt][0]=0.f; acc[nt][1]=0.f; acc[nt][2]=0.f; acc[nt][3]=0.f; }
        #pragma unroll
        for (int ks = 0; ks < 4; ++ks) {
            #pragma unroll
            for (int nt = 0; nt < 8; ++nt) {
                const short8 bf = Bp1[(ks * 8 + nt) * 64 + lane];
                acc[nt] = __builtin_amdgcn_mfma_f32_16x16x32_bf16(a[ks], bf, acc[nt], 0, 0, 0);
            }
        }
        float sv4[4];
        #pragma unroll
        for (int i = 0; i < 4; ++i) sv4[i] = sv[w * 16 + q * 4 + i];
        #pragma unroll
        for (int nt = 0; nt < 8; ++nt) {
            const float bb = bias1[nt * 16 + m];
            #pragma unroll
            for (int i = 0; i < 4; ++i) {
                const float v = fmaxf(acc[nt][i] + sv4[i] * bb, 0.f);
                aggs[(w * 16 + q * 4 + i) * (AGS * 2) + nt * 16 + m] = f2bf(v);
            }
        }
    }
    __syncthreads();

    // ---- phase C2 (waves 0-3): GEMM2 + bias + row L2-norm ----
    if (!act) return;
    const int row0 = b * 64 + w * 16;

    short8 a[4];
    #pragma unroll
    for (int ks = 0; ks < 4; ++ks) {
        const uint4 t4 = *reinterpret_cast<const uint4*>(&aggs[(w * 16 + m) * (AGS * 2) + ks * 32 + q * 8]);
        a[ks] = *reinterpret_cast<const short8*>(&t4);
    }

    floatx4 acc[8];
    #pragma unroll
    for (int nt = 0; nt < 8; ++nt) { acc[nt][0]=0.f; acc[nt][1]=0.f; acc[nt][2]=0.f; acc[nt][3]=0.f; }

    #pragma unroll
    for (int ks = 0; ks < 4; ++ks) {
        #pragma unroll
        for (int nt = 0; nt < 8; ++nt) {
            const short8 bf = Bp2[(ks * 8 + nt) * 64 + lane];
            acc[nt] = __builtin_amdgcn_mfma_f32_16x16x32_bf16(a[ks], bf, acc[nt], 0, 0, 0);
        }
    }

    #pragma unroll
    for (int nt = 0; nt < 8; ++nt) {
        const float bb = bias2[nt * 16 + m];
        #pragma unroll
        for (int i = 0; i < 4; ++i) acc[nt][i] += bb;
    }

    float sq[4] = {0.f, 0.f, 0.f, 0.f};
    #pragma unroll
    for (int nt = 0; nt < 8; ++nt)
        #pragma unroll
        for (int i = 0; i < 4; ++i) sq[i] += acc[nt][i] * acc[nt][i];
    #pragma unroll
    for (int i = 0; i < 4; ++i) {
        #pragma unroll
        for (int mask = 1; mask < 16; mask <<= 1)
            sq[i] += __shfl_xor(sq[i], mask);
        sq[i] = 1.0f / sqrtf(sq[i]);
    }

    #pragma unroll
    for (int nt = 0; nt < 8; ++nt) {
        #pragma unroll
        for (int i = 0; i < 4; ++i) {
            const int r = row0 + q * 4 + i;
            out[(size_t)r * DIM + nt * 16 + m] = acc[nt][i] * sq[i];
        }
    }
}

// ---------------------------------------------------------------------------
extern "C" void kernel_launch(void* const* d_in, const int* in_sizes, int n_in,
                              void* d_out, int out_size, void* d_ws, size_t ws_size,
                              hipStream_t stream) {
    const float* x    = (const float*)d_in[0];
    const float* vals = (const float*)d_in[1];
    const float* W_gc = (const float*)d_in[2];
    const float* b_gc = (const float*)d_in[3];
    const float* W2   = (const float*)d_in[4];
    const float* b2   = (const float*)d_in[5];
    const int*   src  = (const int*)d_in[6];
    const int*   dst  = (const int*)d_in[7];

    float* out = (float*)d_out;

    // ws layout (16B-aligned)
    const size_t XB_B  = (size_t)N_NODES * DIM * 2;      // 12,800,000 (bf16 x)
    const size_t BUK_B = (size_t)N_BKT * BCAP * 8;       // 9,609,216
    char* wsb = (char*)d_ws;
    unsigned int* xb = (unsigned int*)wsb;
    int2*  bucketed = (int2*)(wsb + XB_B);
    int*   bcnt     = (int*)(wsb + XB_B + BUK_B);
    uint4* pw1      = (uint4*)(wsb + XB_B + BUK_B + 4096);
    uint4* pw2      = (uint4*)(wsb + XB_B + BUK_B + 4096 + 32768);

    // 0. zero bucket counters (graph-capturable async memset, 3.2 KB)
    hipMemsetAsync(bcnt, 0, 800 * sizeof(int), stream);

    // 1. scatter || x->bf16 convert || W1/W2 fragment packs  (no GEMM here)
    fused1<<<D1_BLOCKS, 256, 0, stream>>>(
        x, W_gc, W2, src, dst, vals, xb, bcnt, bucketed, pw1, pw2);

    // 2. per-bucket: sort -> gather(xb)+sumval -> GEMM1+relu -> GEMM2+norm
    agg_gemms<<<N_BKT, 512, 0, stream>>>(
        xb, bucketed, bcnt, (const short8*)pw1, (const short8*)pw2,
        b_gc, b2, out);
}

// Round 7
// 150.215 us; speedup vs baseline: 5.2756x; 1.0229x over previous
//
#include <hip/hip_runtime.h>
#include <hip/hip_bf16.h>

#define N_NODES 50000
#define N_EDGES 800000
#define DIM     128
#define N_BKT    782                          // bucket = dst >> 6 (64 nodes/bucket)
#define CHUNK_E  4096                         // edges per scatter chunk
#define EDGE_CHUNKS 196                       // 195*4096 + 1280
#define BCAP     1536                         // bucket region cap (mean 1024, 16 sigma)
#define EBUF_CAP 1408                         // LDS sorted-edge cap (mean 1024, 12 sigma)
#define CONV_BLOCKS 224
#define D1_BLOCKS (EDGE_CHUNKS + CONV_BLOCKS + 16)  // 436
#define AGS      68                           // agg LDS row stride (dwords)

typedef short short8 __attribute__((ext_vector_type(8)));
typedef float floatx4 __attribute__((ext_vector_type(4)));

// fp32 -> bf16 (RNE) bit pattern
__device__ inline unsigned short f2bf(float f) {
    __hip_bfloat16 h = __float2bfloat16(f);
    return *reinterpret_cast<unsigned short*>(&h);
}

__device__ inline uint4 pack8(const float a[8]) {
    uint4 o;
    o.x = (unsigned)f2bf(a[0]) | ((unsigned)f2bf(a[1]) << 16);
    o.y = (unsigned)f2bf(a[2]) | ((unsigned)f2bf(a[3]) << 16);
    o.z = (unsigned)f2bf(a[4]) | ((unsigned)f2bf(a[5]) << 16);
    o.w = (unsigned)f2bf(a[6]) | ((unsigned)f2bf(a[7]) << 16);
    return o;
}

// ---------------------------------------------------------------------------
// Dispatch 1 (436 blocks):
//  [0,196):   bucket scatter, LDS-SORTED: counting-sort the 4096-edge chunk
//             by bucket in LDS, then emit run-contiguous writes (lanes cover
//             ~14 lines/store-instr instead of 64 -> kills write-RMW storm).
//  [196,420): x f32 -> bf16 convert (xb, dword l of row = dims 2l|2l+1)
//  [420,428): pack W1 fragments (B[k][n] = W1[k][n]) -> pw1
//  [428,436): pack W2 fragments (B[k][n] = W2[n][k]) -> pw2
// ---------------------------------------------------------------------------
__global__ __launch_bounds__(256) void fused1(
    const float* __restrict__ x, const float* __restrict__ W1,
    const float* __restrict__ W2,
    const int* __restrict__ src, const int* __restrict__ dst,
    const float* __restrict__ vals,
    unsigned int* __restrict__ xb, int* __restrict__ bcnt,
    int2* __restrict__ bucketed,
    uint4* __restrict__ p1, uint4* __restrict__ p2)
{
    __shared__ __align__(16) int2 ebuf[CHUNK_E];   // 32 KB sorted chunk
    __shared__ int hist[1024];
    __shared__ int lstart[1024];
    __shared__ int gbase[1024];
    __shared__ int lcur[1024];
    __shared__ int tsum[256];
    const int t = threadIdx.x;

    if (blockIdx.x < EDGE_CHUNKS) {
        // ---------------- LDS-sorted bucket scatter ----------------
        const int chunk = blockIdx.x;
        const int base  = chunk * CHUNK_E;
        const int nav   = min(CHUNK_E, N_EDGES - base);  // 4096 or 1280; %4==0
        for (int i = t; i < 1024; i += 256) hist[i] = 0;
        __syncthreads();

        // phase 1: bucket histogram
        const int4* d4 = reinterpret_cast<const int4*>(dst + base);
        #pragma unroll
        for (int i = 0; i < 4; ++i) {
            const int j = t + i * 256;
            if (j * 4 < nav) {
                const int4 d = d4[j];
                atomicAdd(&hist[d.x >> 6], 1);
                atomicAdd(&hist[d.y >> 6], 1);
                atomicAdd(&hist[d.z >> 6], 1);
                atomicAdd(&hist[d.w >> 6], 1);
            }
        }
        __syncthreads();

        // phase 2: scan (4 buckets/thread + Hillis-Steele over 256 sums)
        const int h0 = hist[4*t], h1 = hist[4*t+1], h2 = hist[4*t+2], h3 = hist[4*t+3];
        const int s  = h0 + h1 + h2 + h3;
        tsum[t] = s;
        __syncthreads();
        for (int off = 1; off < 256; off <<= 1) {
            int u = 0;
            if (t >= off) u = tsum[t - off];
            __syncthreads();
            if (t >= off) tsum[t] += u;
            __syncthreads();
        }
        const int ex = tsum[t] - s;                 // exclusive thread base
        lstart[4*t]   = ex;
        lstart[4*t+1] = ex + h0;
        lstart[4*t+2] = ex + h0 + h1;
        lstart[4*t+3] = ex + h0 + h1 + h2;
        lcur[4*t]   = ex;
        lcur[4*t+1] = ex + h0;
        lcur[4*t+2] = ex + h0 + h1;
        lcur[4*t+3] = ex + h0 + h1 + h2;
        // global range reservation per bucket (hist still holds counts)
        for (int b = t; b < N_BKT; b += 256)
            gbase[b] = b * BCAP + atomicAdd(&bcnt[b], hist[b]);
        __syncthreads();

        // phase 3: place payloads sorted into ebuf (bucket id in bits 22-31)
        const int4*   s4 = reinterpret_cast<const int4*>(src + base);
        const float4* v4 = reinterpret_cast<const float4*>(vals + base);
        #pragma unroll
        for (int i = 0; i < 4; ++i) {
            const int j = t + i * 256;
            if (j * 4 < nav) {
                const int4   sw = s4[j];
                const int4   dw = d4[j];
                const float4 vw = v4[j];
                int b, p;
                b = dw.x >> 6; p = atomicAdd(&lcur[b], 1);
                ebuf[p] = make_int2((sw.x & 0xFFFF) | ((dw.x & 63) << 16) | (b << 22), __float_as_int(vw.x));
                b = dw.y >> 6; p = atomicAdd(&lcur[b], 1);
                ebuf[p] = make_int2((sw.y & 0xFFFF) | ((dw.y & 63) << 16) | (b << 22), __float_as_int(vw.y));
                b = dw.z >> 6; p = atomicAdd(&lcur[b], 1);
                ebuf[p] = make_int2((sw.z & 0xFFFF) | ((dw.z & 63) << 16) | (b << 22), __float_as_int(vw.z));
                b = dw.w >> 6; p = atomicAdd(&lcur[b], 1);
                ebuf[p] = make_int2((sw.w & 0xFFFF) | ((dw.w & 63) << 16) | (b << 22), __float_as_int(vw.w));
            }
        }
        __syncthreads();

        // phase 4: run-contiguous writeout (consecutive i -> consecutive addr)
        for (int i = t; i < nav; i += 256) {
            const int2 e = ebuf[i];
            const int  b = ((unsigned)e.x) >> 22;
            bucketed[gbase[b] + (i - lstart[b])] = make_int2(e.x & 0x3FFFFF, e.y);
        }
    } else if (blockIdx.x < EDGE_CHUNKS + CONV_BLOCKS) {
        // ---------------- x -> bf16 convert (streaming) ----------------
        const int cb = blockIdx.x - EDGE_CHUNKS;
        const float4* x4 = reinterpret_cast<const float4*>(x);
        uint2* xb2 = reinterpret_cast<uint2*>(xb);
        for (int i = cb * 256 + t; i < N_NODES * DIM / 4; i += CONV_BLOCKS * 256) {
            const float4 f = x4[i];
            uint2 o;
            o.x = (unsigned)f2bf(f.x) | ((unsigned)f2bf(f.y) << 16);
            o.y = (unsigned)f2bf(f.z) | ((unsigned)f2bf(f.w) << 16);
            xb2[i] = o;
        }
    } else if (blockIdx.x < EDGE_CHUNKS + CONV_BLOCKS + 8) {
        // ---------------- pack W1: B[k][n] = W1[k][n] ----------------
        const int pb   = blockIdx.x - (EDGE_CHUNKS + CONV_BLOCKS);  // 0..7
        const int sI   = pb * 256 + t;                   // 0..2047
        const int lane = sI & 63;
        const int nt   = (sI >> 6) & 7;
        const int ks   = sI >> 9;
        const int m    = lane & 15;
        const int q    = lane >> 4;
        unsigned short e[8];
        #pragma unroll
        for (int j = 0; j < 8; ++j)
            e[j] = f2bf(W1[(ks * 32 + q * 8 + j) * DIM + nt * 16 + m]);
        uint4 o;
        o.x = (unsigned)e[0] | ((unsigned)e[1] << 16);
        o.y = (unsigned)e[2] | ((unsigned)e[3] << 16);
        o.z = (unsigned)e[4] | ((unsigned)e[5] << 16);
        o.w = (unsigned)e[6] | ((unsigned)e[7] << 16);
        p1[sI] = o;
    } else {
        // ---------------- pack W2: B[k][n] = W2[n][k] ----------------
        const int pb   = blockIdx.x - (EDGE_CHUNKS + CONV_BLOCKS + 8); // 0..7
        const int sI   = pb * 256 + t;
        const int lane = sI & 63;
        const int nt   = (sI >> 6) & 7;
        const int ks   = sI >> 9;
        const int m    = lane & 15;
        const int q    = lane >> 4;
        const float4 f0 = *reinterpret_cast<const float4*>(&W2[(nt * 16 + m) * DIM + ks * 32 + q * 8]);
        const float4 f1 = *reinterpret_cast<const float4*>(&W2[(nt * 16 + m) * DIM + ks * 32 + q * 8 + 4]);
        unsigned short e[8];
        e[0] = f2bf(f0.x); e[1] = f2bf(f0.y); e[2] = f2bf(f0.z); e[3] = f2bf(f0.w);
        e[4] = f2bf(f1.x); e[5] = f2bf(f1.y); e[6] = f2bf(f1.z); e[7] = f2bf(f1.w);
        uint4 o;
        o.x = (unsigned)e[0] | ((unsigned)e[1] << 16);
        o.y = (unsigned)e[2] | ((unsigned)e[3] << 16);
        o.z = (unsigned)e[4] | ((unsigned)e[5] << 16);
        o.w = (unsigned)e[6] | ((unsigned)e[7] << 16);
        p2[sI] = o;
    }
}

// ---------------------------------------------------------------------------
// Dispatch 2: one block (512 thr, 8 waves) per 64-node bucket.
//  A: counting-sort the bucket's edges into LDS (ebuf)
//  B: gather RAW bf16 x rows: wave w owns nodes w*8..+8; 4 edges per VMEM
//     instr; also accumulates sumval per node. shfl-reduce, bf16 -> agg LDS.
//  C1 (waves 0-3): GEMM1 from agg: out1 = aggx @ W1 + sumval*b_gc; relu;
//     bf16 back into agg (in-place, strip-local).
//  C2 (waves 0-3): GEMM2: out = rownorm(relu1 @ W2^T + b2).
// LDS ~29.7 KB. No FP atomics anywhere.
// ---------------------------------------------------------------------------
__global__ __launch_bounds__(512) void agg_gemms(
    const unsigned int* __restrict__ xb, const int2* __restrict__ bucketed,
    const int* __restrict__ bcnt,
    const short8* __restrict__ Bp1, const short8* __restrict__ Bp2,
    const float* __restrict__ bias1, const float* __restrict__ bias2,
    float* __restrict__ out)
{
    __shared__ int2 ebuf[EBUF_CAP];            // 11264 B
    __shared__ unsigned int agg[64 * AGS];     // 17408 B
    __shared__ float sv[64];
    __shared__ int cnt[64];
    __shared__ int coff[64];
    __shared__ int cur[64];

    const int b = blockIdx.x;
    const int t = threadIdx.x;
    int nE = bcnt[b];
    if (nE > EBUF_CAP) nE = EBUF_CAP;          // 12-sigma guard, never taken
    const int base = b * BCAP;

    // ---- phase A: counting sort by dst&63 into ebuf ----
    if (t < 64) cnt[t] = 0;
    __syncthreads();
    for (int i = t; i < nE; i += 512)
        atomicAdd(&cnt[(bucketed[base + i].x >> 16) & 63], 1);
    __syncthreads();
    if (t < 64) coff[t] = cnt[t];
    __syncthreads();
    for (int off = 1; off < 64; off <<= 1) {
        int u = 0;
        if (t < 64 && t >= off) u = coff[t - off];
        __syncthreads();
        if (t < 64 && t >= off) coff[t] += u;
        __syncthreads();
    }
    if (t < 64) cur[t] = coff[t] - cnt[t];     // exclusive prefix
    __syncthreads();
    for (int i = t; i < nE; i += 512) {
        const int2 e = bucketed[base + i];
        const int  n = (e.x >> 16) & 63;
        const int  p = atomicAdd(&cur[n], 1);
        ebuf[p] = e;
    }
    __syncthreads();

    // ---- phase B: wave w -> nodes w*8..+8; gather xb rows + sumval ----
    const int w    = t >> 6;
    const int lane = t & 63;
    const int g    = lane >> 4;                // edge sub-slot 0..3
    const int dl   = lane & 15;                // dim block: dims 8*dl..+8

    for (int nl = w * 8; nl < w * 8 + 8; ++nl) {
        const int end = cur[nl];               // = excl + cnt after scatter
        const int c   = cnt[nl];
        const int beg = end - c;
        float acc[8];
        #pragma unroll
        for (int k = 0; k < 8; ++k) acc[k] = 0.f;
        float sval = 0.f;

        const int nI = (c + 3) >> 2;           // instructions (4 edges each)
        auto step = [&](int it) {
            const int  idx = beg + it * 4 + g;
            const bool vld = idx < end;
            const int2 e   = ebuf[vld ? idx : beg];
            const float val = vld ? __int_as_float(e.y) : 0.f;
            const uint4 u = *reinterpret_cast<const uint4*>(
                &xb[(size_t)(e.x & 0xFFFF) * 64 + dl * 4]);
            sval += val;
            acc[0] += __uint_as_float(u.x << 16)          * val;
            acc[1] += __uint_as_float(u.x & 0xffff0000u)  * val;
            acc[2] += __uint_as_float(u.y << 16)          * val;
            acc[3] += __uint_as_float(u.y & 0xffff0000u)  * val;
            acc[4] += __uint_as_float(u.z << 16)          * val;
            acc[5] += __uint_as_float(u.z & 0xffff0000u)  * val;
            acc[6] += __uint_as_float(u.w << 16)          * val;
            acc[7] += __uint_as_float(u.w & 0xffff0000u)  * val;
        };
        int it = 0;
        for (; it + 3 < nI; it += 4) { step(it); step(it+1); step(it+2); step(it+3); }
        for (; it < nI; ++it) step(it);

        // combine partial sums across the 4 lane-quarters (g dimension)
        #pragma unroll
        for (int k = 0; k < 8; ++k) {
            acc[k] += __shfl_xor(acc[k], 16);
            acc[k] += __shfl_xor(acc[k], 32);
        }
        sval += __shfl_xor(sval, 16);
        sval += __shfl_xor(sval, 32);
        if (lane == 0) sv[nl] = sval;
        if (lane < 16) {                       // lanes 0..15 write the row (NO relu)
            *reinterpret_cast<uint4*>(&agg[nl * AGS + dl * 4]) = pack8(acc);
        }
    }
    __syncthreads();

    // ---- phase C1 (waves 0-3): GEMM1 + sumval*b1, relu, bf16 -> agg ----
    const bool act = (w < 4) && (b * 64 + w * 16 < N_NODES);  // bucket 781 tail
    const int m = lane & 15;
    const int q = lane >> 4;
    unsigned short* aggs = reinterpret_cast<unsigned short*>(agg);

    if (act) {
        short8 a[4];
        #pragma unroll
        for (int ks = 0; ks < 4; ++ks) {
            const uint4 t4 = *reinterpret_cast<const uint4*>(&agg[(w * 16 + m) * AGS + ks * 16 + q * 4]);
            a[ks] = *reinterpret_cast<const short8*>(&t4);
        }
        floatx4 acc[8];
        #pragma unroll
        for (int nt = 0; nt < 8; ++nt) { acc[nt][0]=0.f; acc[nt][1]=0.f; acc[nt][2]=0.f; acc[nt][3]=0.f; }
        #pragma unroll
        for (int ks = 0; ks < 4; ++ks) {
            #pragma unroll
            for (int nt = 0; nt < 8; ++nt) {
                const short8 bf = Bp1[(ks * 8 + nt) * 64 + lane];
                acc[nt] = __builtin_amdgcn_mfma_f32_16x16x32_bf16(a[ks], bf, acc[nt], 0, 0, 0);
            }
        }
        float sv4[4];
        #pragma unroll
        for (int i = 0; i < 4; ++i) sv4[i] = sv[w * 16 + q * 4 + i];
        #pragma unroll
        for (int nt = 0; nt < 8; ++nt) {
            const float bb = bias1[nt * 16 + m];
            #pragma unroll
            for (int i = 0; i < 4; ++i) {
                const float v = fmaxf(acc[nt][i] + sv4[i] * bb, 0.f);
                aggs[(w * 16 + q * 4 + i) * (AGS * 2) + nt * 16 + m] = f2bf(v);
            }
        }
    }
    __syncthreads();

    // ---- phase C2 (waves 0-3): GEMM2 + bias + row L2-norm ----
    if (!act) return;
    const int row0 = b * 64 + w * 16;

    short8 a[4];
    #pragma unroll
    for (int ks = 0; ks < 4; ++ks) {
        const uint4 t4 = *reinterpret_cast<const uint4*>(&aggs[(w * 16 + m) * (AGS * 2) + ks * 32 + q * 8]);
        a[ks] = *reinterpret_cast<const short8*>(&t4);
    }

    floatx4 acc[8];
    #pragma unroll
    for (int nt = 0; nt < 8; ++nt) { acc[nt][0]=0.f; acc[nt][1]=0.f; acc[nt][2]=0.f; acc[nt][3]=0.f; }

    #pragma unroll
    for (int ks = 0; ks < 4; ++ks) {
        #pragma unroll
        for (int nt = 0; nt < 8; ++nt) {
            const short8 bf = Bp2[(ks * 8 + nt) * 64 + lane];
            acc[nt] = __builtin_amdgcn_mfma_f32_16x16x32_bf16(a[ks], bf, acc[nt], 0, 0, 0);
        }
    }

    #pragma unroll
    for (int nt = 0; nt < 8; ++nt) {
        const float bb = bias2[nt * 16 + m];
        #pragma unroll
        for (int i = 0; i < 4; ++i) acc[nt][i] += bb;
    }

    float sq[4] = {0.f, 0.f, 0.f, 0.f};
    #pragma unroll
    for (int nt = 0; nt < 8; ++nt)
        #pragma unroll
        for (int i = 0; i < 4; ++i) sq[i] += acc[nt][i] * acc[nt][i];
    #pragma unroll
    for (int i = 0; i < 4; ++i) {
        #pragma unroll
        for (int mask = 1; mask < 16; mask <<= 1)
            sq[i] += __shfl_xor(sq[i], mask);
        sq[i] = 1.0f / sqrtf(sq[i]);
    }

    #pragma unroll
    for (int nt = 0; nt < 8; ++nt) {
        #pragma unroll
        for (int i = 0; i < 4; ++i) {
            const int r = row0 + q * 4 + i;
            out[(size_t)r * DIM + nt * 16 + m] = acc[nt][i] * sq[i];
        }
    }
}

// ---------------------------------------------------------------------------
extern "C" void kernel_launch(void* const* d_in, const int* in_sizes, int n_in,
                              void* d_out, int out_size, void* d_ws, size_t ws_size,
                              hipStream_t stream) {
    const float* x    = (const float*)d_in[0];
    const float* vals = (const float*)d_in[1];
    const float* W_gc = (const float*)d_in[2];
    const float* b_gc = (const float*)d_in[3];
    const float* W2   = (const float*)d_in[4];
    const float* b2   = (const float*)d_in[5];
    const int*   src  = (const int*)d_in[6];
    const int*   dst  = (const int*)d_in[7];

    float* out = (float*)d_out;

    // ws layout (16B-aligned)
    const size_t XB_B  = (size_t)N_NODES * DIM * 2;      // 12,800,000 (bf16 x)
    const size_t BUK_B = (size_t)N_BKT * BCAP * 8;       // 9,609,216
    char* wsb = (char*)d_ws;
    unsigned int* xb = (unsigned int*)wsb;
    int2*  bucketed = (int2*)(wsb + XB_B);
    int*   bcnt     = (int*)(wsb + XB_B + BUK_B);
    uint4* pw1      = (uint4*)(wsb + XB_B + BUK_B + 4096);
    uint4* pw2      = (uint4*)(wsb + XB_B + BUK_B + 4096 + 32768);

    // 0. zero bucket counters (graph-capturable async memset, 3.2 KB)
    hipMemsetAsync(bcnt, 0, 800 * sizeof(int), stream);

    // 1. LDS-sorted scatter || x->bf16 convert || W1/W2 fragment packs
    fused1<<<D1_BLOCKS, 256, 0, stream>>>(
        x, W_gc, W2, src, dst, vals, xb, bcnt, bucketed, pw1, pw2);

    // 2. per-bucket: sort -> gather(xb)+sumval -> GEMM1+relu -> GEMM2+norm
    agg_gemms<<<N_BKT, 512, 0, stream>>>(
        xb, bucketed, bcnt, (const short8*)pw1, (const short8*)pw2,
        b_gc, b2, out);
}

// Round 9
// 148.687 us; speedup vs baseline: 5.3298x; 1.0103x over previous
//
#include <hip/hip_runtime.h>
#include <hip/hip_bf16.h>

#define N_NODES 50000
#define N_EDGES 800000
#define DIM     128
#define N_BKT    782                          // bucket = dst >> 6 (64 nodes/bucket)
#define CHUNK_E  4096                         // edges per scatter chunk
#define EDGE_CHUNKS 196                       // 195*4096 + 1280
#define BCAP     1536                         // bucket region cap (mean 1024, 16 sigma)
#define EBUF_CAP 1408                         // LDS sorted-edge cap (mean 1024, 12 sigma)
#define CONV_BLOCKS 224
#define D1_BLOCKS (EDGE_CHUNKS + CONV_BLOCKS + 16)  // 436
#define AGS      68                           // agg LDS row stride (dwords)
#define BPAD     32                           // bcnt stride: 1 counter per 128B line

typedef short short8 __attribute__((ext_vector_type(8)));
typedef float floatx4 __attribute__((ext_vector_type(4)));

// fp32 -> bf16 (RNE) bit pattern
__device__ inline unsigned short f2bf(float f) {
    __hip_bfloat16 h = __float2bfloat16(f);
    return *reinterpret_cast<unsigned short*>(&h);
}

__device__ inline uint4 pack8(const float a[8]) {
    uint4 o;
    o.x = (unsigned)f2bf(a[0]) | ((unsigned)f2bf(a[1]) << 16);
    o.y = (unsigned)f2bf(a[2]) | ((unsigned)f2bf(a[3]) << 16);
    o.z = (unsigned)f2bf(a[4]) | ((unsigned)f2bf(a[5]) << 16);
    o.w = (unsigned)f2bf(a[6]) | ((unsigned)f2bf(a[7]) << 16);
    return o;
}

// ---------------------------------------------------------------------------
// Dispatch 1 (436 blocks):
//  [0,196):   LDS-sorted bucket scatter; global range reservation uses
//             LINE-PADDED counters bcnt[b*32] (kills cross-XCD atomic
//             ping-pong on 25 shared lines -> 782 independent lines).
//  [196,420): x f32 -> bf16 convert (xb)
//  [420,428): pack W1 fragments -> pw1
//  [428,436): pack W2 fragments -> pw2
// ---------------------------------------------------------------------------
__global__ __launch_bounds__(256) void fused1(
    const float* __restrict__ x, const float* __restrict__ W1,
    const float* __restrict__ W2,
    const int* __restrict__ src, const int* __restrict__ dst,
    const float* __restrict__ vals,
    unsigned int* __restrict__ xb, int* __restrict__ bcnt,
    int2* __restrict__ bucketed,
    uint4* __restrict__ p1, uint4* __restrict__ p2)
{
    __shared__ __align__(16) int2 ebuf[CHUNK_E];   // 32 KB sorted chunk
    __shared__ int hist[1024];
    __shared__ int lstart[1024];
    __shared__ int gbase[1024];
    __shared__ int lcur[1024];
    __shared__ int tsum[256];
    const int t = threadIdx.x;

    if (blockIdx.x < EDGE_CHUNKS) {
        // ---------------- LDS-sorted bucket scatter ----------------
        const int chunk = blockIdx.x;
        const int base  = chunk * CHUNK_E;
        const int nav   = min(CHUNK_E, N_EDGES - base);  // 4096 or 1280; %4==0
        for (int i = t; i < 1024; i += 256) hist[i] = 0;
        __syncthreads();

        // phase 1: bucket histogram
        const int4* d4 = reinterpret_cast<const int4*>(dst + base);
        #pragma unroll
        for (int i = 0; i < 4; ++i) {
            const int j = t + i * 256;
            if (j * 4 < nav) {
                const int4 d = d4[j];
                atomicAdd(&hist[d.x >> 6], 1);
                atomicAdd(&hist[d.y >> 6], 1);
                atomicAdd(&hist[d.z >> 6], 1);
                atomicAdd(&hist[d.w >> 6], 1);
            }
        }
        __syncthreads();

        // phase 2: scan (4 buckets/thread + Hillis-Steele over 256 sums)
        const int h0 = hist[4*t], h1 = hist[4*t+1], h2 = hist[4*t+2], h3 = hist[4*t+3];
        const int s  = h0 + h1 + h2 + h3;
        tsum[t] = s;
        __syncthreads();
        for (int off = 1; off < 256; off <<= 1) {
            int u = 0;
            if (t >= off) u = tsum[t - off];
            __syncthreads();
            if (t >= off) tsum[t] += u;
            __syncthreads();
        }
        const int ex = tsum[t] - s;                 // exclusive thread base
        lstart[4*t]   = ex;
        lstart[4*t+1] = ex + h0;
        lstart[4*t+2] = ex + h0 + h1;
        lstart[4*t+3] = ex + h0 + h1 + h2;
        lcur[4*t]   = ex;
        lcur[4*t+1] = ex + h0;
        lcur[4*t+2] = ex + h0 + h1;
        lcur[4*t+3] = ex + h0 + h1 + h2;
        // global range reservation per bucket (LINE-PADDED counters)
        for (int b = t; b < N_BKT; b += 256)
            gbase[b] = b * BCAP + atomicAdd(&bcnt[b * BPAD], hist[b]);
        __syncthreads();

        // phase 3: place payloads sorted into ebuf (bucket id in bits 22-31)
        const int4*   s4 = reinterpret_cast<const int4*>(src + base);
        const float4* v4 = reinterpret_cast<const float4*>(vals + base);
        #pragma unroll
        for (int i = 0; i < 4; ++i) {
            const int j = t + i * 256;
            if (j * 4 < nav) {
                const int4   sw = s4[j];
                const int4   dw = d4[j];
                const float4 vw = v4[j];
                int b, p;
                b = dw.x >> 6; p = atomicAdd(&lcur[b], 1);
                ebuf[p] = make_int2((sw.x & 0xFFFF) | ((dw.x & 63) << 16) | (b << 22), __float_as_int(vw.x));
                b = dw.y >> 6; p = atomicAdd(&lcur[b], 1);
                ebuf[p] = make_int2((sw.y & 0xFFFF) | ((dw.y & 63) << 16) | (b << 22), __float_as_int(vw.y));
                b = dw.z >> 6; p = atomicAdd(&lcur[b], 1);
                ebuf[p] = make_int2((sw.z & 0xFFFF) | ((dw.z & 63) << 16) | (b << 22), __float_as_int(vw.z));
                b = dw.w >> 6; p = atomicAdd(&lcur[b], 1);
                ebuf[p] = make_int2((sw.w & 0xFFFF) | ((dw.w & 63) << 16) | (b << 22), __float_as_int(vw.w));
            }
        }
        __syncthreads();

        // phase 4: run-contiguous writeout (consecutive i -> consecutive addr)
        for (int i = t; i < nav; i += 256) {
            const int2 e = ebuf[i];
            const int  b = ((unsigned)e.x) >> 22;
            bucketed[gbase[b] + (i - lstart[b])] = make_int2(e.x & 0x3FFFFF, e.y);
        }
    } else if (blockIdx.x < EDGE_CHUNKS + CONV_BLOCKS) {
        // ---------------- x -> bf16 convert (streaming) ----------------
        const int cb = blockIdx.x - EDGE_CHUNKS;
        const float4* x4 = reinterpret_cast<const float4*>(x);
        uint2* xb2 = reinterpret_cast<uint2*>(xb);
        for (int i = cb * 256 + t; i < N_NODES * DIM / 4; i += CONV_BLOCKS * 256) {
            const float4 f = x4[i];
            uint2 o;
            o.x = (unsigned)f2bf(f.x) | ((unsigned)f2bf(f.y) << 16);
            o.y = (unsigned)f2bf(f.z) | ((unsigned)f2bf(f.w) << 16);
            xb2[i] = o;
        }
    } else if (blockIdx.x < EDGE_CHUNKS + CONV_BLOCKS + 8) {
        // ---------------- pack W1: B[k][n] = W1[k][n] ----------------
        const int pb   = blockIdx.x - (EDGE_CHUNKS + CONV_BLOCKS);  // 0..7
        const int sI   = pb * 256 + t;                   // 0..2047
        const int lane = sI & 63;
        const int nt   = (sI >> 6) & 7;
        const int ks   = sI >> 9;
        const int m    = lane & 15;
        const int q    = lane >> 4;
        unsigned short e[8];
        #pragma unroll
        for (int j = 0; j < 8; ++j)
            e[j] = f2bf(W1[(ks * 32 + q * 8 + j) * DIM + nt * 16 + m]);
        uint4 o;
        o.x = (unsigned)e[0] | ((unsigned)e[1] << 16);
        o.y = (unsigned)e[2] | ((unsigned)e[3] << 16);
        o.z = (unsigned)e[4] | ((unsigned)e[5] << 16);
        o.w = (unsigned)e[6] | ((unsigned)e[7] << 16);
        p1[sI] = o;
    } else {
        // ---------------- pack W2: B[k][n] = W2[n][k] ----------------
        const int pb   = blockIdx.x - (EDGE_CHUNKS + CONV_BLOCKS + 8); // 0..7
        const int sI   = pb * 256 + t;
        const int lane = sI & 63;
        const int nt   = (sI >> 6) & 7;
        const int ks   = sI >> 9;
        const int m    = lane & 15;
        const int q    = lane >> 4;
        const float4 f0 = *reinterpret_cast<const float4*>(&W2[(nt * 16 + m) * DIM + ks * 32 + q * 8]);
        const float4 f1 = *reinterpret_cast<const float4*>(&W2[(nt * 16 + m) * DIM + ks * 32 + q * 8 + 4]);
        unsigned short e[8];
        e[0] = f2bf(f0.x); e[1] = f2bf(f0.y); e[2] = f2bf(f0.z); e[3] = f2bf(f0.w);
        e[4] = f2bf(f1.x); e[5] = f2bf(f1.y); e[6] = f2bf(f1.z); e[7] = f2bf(f1.w);
        uint4 o;
        o.x = (unsigned)e[0] | ((unsigned)e[1] << 16);
        o.y = (unsigned)e[2] | ((unsigned)e[3] << 16);
        o.z = (unsigned)e[4] | ((unsigned)e[5] << 16);
        o.w = (unsigned)e[6] | ((unsigned)e[7] << 16);
        p2[sI] = o;
    }
}

// ---------------------------------------------------------------------------
// Dispatch 2: one block (512 thr, 8 waves) per 64-node bucket.
//  A: counting-sort the bucket's edges into LDS (ebuf)
//  B: gather RAW bf16 x rows: wave w owns nodes w*8..+8; 4 edges per VMEM
//     instr; also accumulates sumval per node. shfl-reduce, bf16 -> agg LDS.
//  C1 (waves 0-3): GEMM1 from agg: out1 = aggx @ W1 + sumval*b_gc; relu;
//     bf16 back into agg (in-place, strip-local).
//  C2 (waves 0-3): GEMM2: out = rownorm(relu1 @ W2^T + b2).
// LDS ~29.7 KB. No FP atomics anywhere.
// ---------------------------------------------------------------------------
__global__ __launch_bounds__(512) void agg_gemms(
    const unsigned int* __restrict__ xb, const int2* __restrict__ bucketed,
    const int* __restrict__ bcnt,
    const short8* __restrict__ Bp1, const short8* __restrict__ Bp2,
    const float* __restrict__ bias1, const float* __restrict__ bias2,
    float* __restrict__ out)
{
    __shared__ int2 ebuf[EBUF_CAP];            // 11264 B
    __shared__ unsigned int agg[64 * AGS];     // 17408 B
    __shared__ float sv[64];
    __shared__ int cnt[64];
    __shared__ int coff[64];
    __shared__ int cur[64];

    const int b = blockIdx.x;
    const int t = threadIdx.x;
    int nE = bcnt[b * BPAD];
    if (nE > EBUF_CAP) nE = EBUF_CAP;          // 12-sigma guard, never taken
    const int base = b * BCAP;

    // ---- phase A: counting sort by dst&63 into ebuf ----
    if (t < 64) cnt[t] = 0;
    __syncthreads();
    for (int i = t; i < nE; i += 512)
        atomicAdd(&cnt[(bucketed[base + i].x >> 16) & 63], 1);
    __syncthreads();
    if (t < 64) coff[t] = cnt[t];
    __syncthreads();
    for (int off = 1; off < 64; off <<= 1) {
        int u = 0;
        if (t < 64 && t >= off) u = coff[t - off];
        __syncthreads();
        if (t < 64 && t >= off) coff[t] += u;
        __syncthreads();
    }
    if (t < 64) cur[t] = coff[t] - cnt[t];     // exclusive prefix
    __syncthreads();
    for (int i = t; i < nE; i += 512) {
        const int2 e = bucketed[base + i];
        const int  n = (e.x >> 16) & 63;
        const int  p = atomicAdd(&cur[n], 1);
        ebuf[p] = e;
    }
    __syncthreads();

    // ---- phase B: wave w -> nodes w*8..+8; gather xb rows + sumval ----
    const int w    = t >> 6;
    const int lane = t & 63;
    const int g    = lane >> 4;                // edge sub-slot 0..3
    const int dl   = lane & 15;                // dim block: dims 8*dl..+8

    for (int nl = w * 8; nl < w * 8 + 8; ++nl) {
        const int end = cur[nl];               // = excl + cnt after scatter
        const int c   = cnt[nl];
        const int beg = end - c;
        float acc[8];
        #pragma unroll
        for (int k = 0; k < 8; ++k) acc[k] = 0.f;
        float sval = 0.f;

        const int nI = (c + 3) >> 2;           // instructions (4 edges each)
        auto step = [&](int it) {
            const int  idx = beg + it * 4 + g;
            const bool vld = idx < end;
            const int2 e   = ebuf[vld ? idx : beg];
            const float val = vld ? __int_as_float(e.y) : 0.f;
            const uint4 u = *reinterpret_cast<const uint4*>(
                &xb[(size_t)(e.x & 0xFFFF) * 64 + dl * 4]);
            sval += val;
            acc[0] += __uint_as_float(u.x << 16)          * val;
            acc[1] += __uint_as_float(u.x & 0xffff0000u)  * val;
            acc[2] += __uint_as_float(u.y << 16)          * val;
            acc[3] += __uint_as_float(u.y & 0xffff0000u)  * val;
            acc[4] += __uint_as_float(u.z << 16)          * val;
            acc[5] += __uint_as_float(u.z & 0xffff0000u)  * val;
            acc[6] += __uint_as_float(u.w << 16)          * val;
            acc[7] += __uint_as_float(u.w & 0xffff0000u)  * val;
        };
        int it = 0;
        for (; it + 3 < nI; it += 4) { step(it); step(it+1); step(it+2); step(it+3); }
        for (; it < nI; ++it) step(it);

        // combine partial sums across the 4 lane-quarters (g dimension)
        #pragma unroll
        for (int k = 0; k < 8; ++k) {
            acc[k] += __shfl_xor(acc[k], 16);
            acc[k] += __shfl_xor(acc[k], 32);
        }
        sval += __shfl_xor(sval, 16);
        sval += __shfl_xor(sval, 32);
        if (lane == 0) sv[nl] = sval;
        if (lane < 16) {                       // lanes 0..15 write the row (NO relu)
            *reinterpret_cast<uint4*>(&agg[nl * AGS + dl * 4]) = pack8(acc);
        }
    }
    __syncthreads();

    // ---- phase C1 (waves 0-3): GEMM1 + sumval*b1, relu, bf16 -> agg ----
    const bool act = (w < 4) && (b * 64 + w * 16 < N_NODES);  // bucket 781 tail
    const int m = lane & 15;
    const int q = lane >> 4;
    unsigned short* aggs = reinterpret_cast<unsigned short*>(agg);

    if (act) {
        short8 a[4];
        #pragma unroll
        for (int ks = 0; ks < 4; ++ks) {
            const uint4 t4 = *reinterpret_cast<const uint4*>(&agg[(w * 16 + m) * AGS + ks * 16 + q * 4]);
            a[ks] = *reinterpret_cast<const short8*>(&t4);
        }
        floatx4 acc[8];
        #pragma unroll
        for (int nt = 0; nt < 8; ++nt) { acc[nt][0]=0.f; acc[nt][1]=0.f; acc[nt][2]=0.f; acc[nt][3]=0.f; }
        #pragma unroll
        for (int ks = 0; ks < 4; ++ks) {
            #pragma unroll
            for (int nt = 0; nt < 8; ++nt) {
                const short8 bf = Bp1[(ks * 8 + nt) * 64 + lane];
                acc[nt] = __builtin_amdgcn_mfma_f32_16x16x32_bf16(a[ks], bf, acc[nt], 0, 0, 0);
            }
        }
        float sv4[4];
        #pragma unroll
        for (int i = 0; i < 4; ++i) sv4[i] = sv[w * 16 + q * 4 + i];
        #pragma unroll
        for (int nt = 0; nt < 8; ++nt) {
            const float bb = bias1[nt * 16 + m];
            #pragma unroll
            for (int i = 0; i < 4; ++i) {
                const float v = fmaxf(acc[nt][i] + sv4[i] * bb, 0.f);
                aggs[(w * 16 + q * 4 + i) * (AGS * 2) + nt * 16 + m] = f2bf(v);
            }
        }
    }
    __syncthreads();

    // ---- phase C2 (waves 0-3): GEMM2 + bias + row L2-norm ----
    if (!act) return;
    const int row0 = b * 64 + w * 16;

    short8 a[4];
    #pragma unroll
    for (int ks = 0; ks < 4; ++ks) {
        const uint4 t4 = *reinterpret_cast<const uint4*>(&aggs[(w * 16 + m) * (AGS * 2) + ks * 32 + q * 8]);
        a[ks] = *reinterpret_cast<const short8*>(&t4);
    }

    floatx4 acc[8];
    #pragma unroll
    for (int nt = 0; nt < 8; ++nt) { acc[nt][0]=0.f; acc[nt][1]=0.f; acc[nt][2]=0.f; acc[nt][3]=0.f; }

    #pragma unroll
    for (int ks = 0; ks < 4; ++ks) {
        #pragma unroll
        for (int nt = 0; nt < 8; ++nt) {
            const short8 bf = Bp2[(ks * 8 + nt) * 64 + lane];
            acc[nt] = __builtin_amdgcn_mfma_f32_16x16x32_bf16(a[ks], bf, acc[nt], 0, 0, 0);
        }
    }

    #pragma unroll
    for (int nt = 0; nt < 8; ++nt) {
        const float bb = bias2[nt * 16 + m];
        #pragma unroll
        for (int i = 0; i < 4; ++i) acc[nt][i] += bb;
    }

    float sq[4] = {0.f, 0.f, 0.f, 0.f};
    #pragma unroll
    for (int nt = 0; nt < 8; ++nt)
        #pragma unroll
        for (int i = 0; i < 4; ++i) sq[i] += acc[nt][i] * acc[nt][i];
    #pragma unroll
    for (int i = 0; i < 4; ++i) {
        #pragma unroll
        for (int mask = 1; mask < 16; mask <<= 1)
            sq[i] += __shfl_xor(sq[i], mask);
        sq[i] = 1.0f / sqrtf(sq[i]);
    }

    #pragma unroll
    for (int nt = 0; nt < 8; ++nt) {
        #pragma unroll
        for (int i = 0; i < 4; ++i) {
            const int r = row0 + q * 4 + i;
            out[(size_t)r * DIM + nt * 16 + m] = acc[nt][i] * sq[i];
        }
    }
}

// ---------------------------------------------------------------------------
extern "C" void kernel_launch(void* const* d_in, const int* in_sizes, int n_in,
                              void* d_out, int out_size, void* d_ws, size_t ws_size,
                              hipStream_t stream) {
    const float* x    = (const float*)d_in[0];
    const float* vals = (const float*)d_in[1];
    const float* W_gc = (const float*)d_in[2];
    const float* b_gc = (const float*)d_in[3];
    const float* W2   = (const float*)d_in[4];
    const float* b2   = (const float*)d_in[5];
    const int*   src  = (const int*)d_in[6];
    const int*   dst  = (const int*)d_in[7];

    float* out = (float*)d_out;

    // ws layout (16B-aligned)
    const size_t XB_B  = (size_t)N_NODES * DIM * 2;      // 12,800,000 (bf16 x)
    const size_t BUK_B = (size_t)N_BKT * BCAP * 8;       // 9,609,216
    const size_t BC_B  = (size_t)800 * BPAD * 4;         // 102,400 (line-padded)
    char* wsb = (char*)d_ws;
    unsigned int* xb = (unsigned int*)wsb;
    int2*  bucketed = (int2*)(wsb + XB_B);
    int*   bcnt     = (int*)(wsb + XB_B + BUK_B);
    uint4* pw1      = (uint4*)(wsb + XB_B + BUK_B + BC_B);
    uint4* pw2      = (uint4*)(wsb + XB_B + BUK_B + BC_B + 32768);

    // 0. zero line-padded bucket counters (graph-capturable async memset)
    hipMemsetAsync(bcnt, 0, BC_B, stream);

    // 1. LDS-sorted scatter (padded-atomic reservation) || convert || packs
    fused1<<<D1_BLOCKS, 256, 0, stream>>>(
        x, W_gc, W2, src, dst, vals, xb, bcnt, bucketed, pw1, pw2);

    // 2. per-bucket: sort -> gather(xb)+sumval -> GEMM1+relu -> GEMM2+norm
    agg_gemms<<<N_BKT, 512, 0, stream>>>(
        xb, bucketed, bcnt, (const short8*)pw1, (const short8*)pw2,
        b_gc, b2, out);
}